// Round 9
// baseline (1146.735 us; speedup 1.0000x reference)
//
#include <hip/hip_runtime.h>

#define MDIM 1024
#define H4   4096
#define TKL  10
#define NT   30
#define NWFR 39
#define GBLK 256
#define GTHR 1024
#define AGENT __HIP_MEMORY_SCOPE_AGENT

typedef _Float16 h2v __attribute__((ext_vector_type(2)));
typedef unsigned int uv4 __attribute__((ext_vector_type(4)));
typedef float fv4 __attribute__((ext_vector_type(4)));
union U16 { uv4 u; h2v h[4]; _Float16 f[8]; };

__device__ __forceinline__ float wred(float v) {
#pragma unroll
  for (int o = 32; o; o >>= 1) v += __shfl_xor(v, o, 64);
  return v;
}

__device__ __forceinline__ float dot16(const U16& w, const U16& x, float acc) {
  acc = __builtin_amdgcn_fdot2(w.h[0], x.h[0], acc, false);
  acc = __builtin_amdgcn_fdot2(w.h[1], x.h[1], acc, false);
  acc = __builtin_amdgcn_fdot2(w.h[2], x.h[2], acc, false);
  acc = __builtin_amdgcn_fdot2(w.h[3], x.h[3], acc, false);
  return acc;
}

// write-through 16B store (bypass L1/L2 dirty state -> visible at coherence point)
__device__ __forceinline__ void stg16(const void* p, uv4 v) {
  asm volatile("global_store_dwordx4 %0, %1, off sc0 sc1" :: "v"(p), "v"(v) : "memory");
}

__global__ void k_cvt(const float* __restrict__ in, _Float16* __restrict__ out, int n8) {
  int g = blockIdx.x * blockDim.x + threadIdx.x;
  if (g >= n8) return;
  const float4* p = (const float4*)in;
  float4 a = p[2 * g], b = p[2 * g + 1];
  U16 o;
  o.f[0] = (_Float16)a.x; o.f[1] = (_Float16)a.y;
  o.f[2] = (_Float16)a.z; o.f[3] = (_Float16)a.w;
  o.f[4] = (_Float16)b.x; o.f[5] = (_Float16)b.y;
  o.f[6] = (_Float16)b.z; o.f[7] = (_Float16)b.w;
  ((uv4*)out)[g] = o.u;
}

__global__ void k_xcf(const float* __restrict__ x, float* __restrict__ xcf) {
  int idx = blockIdx.x * blockDim.x + threadIdx.x;
  if (idx >= NT * MDIM) return;
  int i = idx >> 10, m = idx & (MDIM - 1);
  int c = m & 31, s = m >> 5;
  const float* p = x + c * (32 * 360) + s * 360 + i * 12;
  float acc = 0.f;
#pragma unroll
  for (int k = 0; k < 12; ++k) acc += p[k];
  xcf[idx] = acc * (1.0f / 12.0f);
}

__global__ void k_s0(const float* __restrict__ xcf, const float* __restrict__ W,
                     float* __restrict__ S, float* __restrict__ Smir) {
  int wid = (blockIdx.x * blockDim.x + threadIdx.x) >> 6;
  int lane = threadIdx.x & 63;
  if (wid >= NT * MDIM) return;
  int i = wid >> 10, m = wid & (MDIM - 1);
  const float4* wr = (const float4*)(W + (size_t)m * MDIM);
  const float4* xr = (const float4*)(xcf + i * MDIM);
  float acc = 0.f;
#pragma unroll
  for (int k = 0; k < 4; ++k) {
    float4 w = wr[lane + (k << 6)];
    float4 xv = xr[lane + (k << 6)];
    acc += w.x * xv.x + w.y * xv.y + w.z * xv.z + w.w * xv.w;
  }
  acc = wred(acc);
  if (lane == 0) {
    int e = m & ~1;
    float ang = (float)i / powf(10000.0f, (float)e / 512.0f);
    float pe = (m & 1) ? cosf(ang) : sinf(ang);
    float val = acc + pe;
    S[wid] = val;
    Smir[((size_t)i * NT + i) * MDIM + m] = val;
  }
}

// two-level fence-free barrier (proven R4/R5)
__device__ __forceinline__ void gbar(unsigned* bar, unsigned ep) {
  asm volatile("s_waitcnt vmcnt(0)" ::: "memory");
  __syncthreads();
  if (threadIdx.x == 0) {
    unsigned* leaf = bar + ((blockIdx.x & 7) << 5);
    const unsigned prev = __hip_atomic_fetch_add(leaf, 1u, __ATOMIC_RELAXED, AGENT);
    if (prev == ep * 32u - 1u) {
      const unsigned r = __hip_atomic_fetch_add(bar + 256, 1u, __ATOMIC_RELAXED, AGENT);
      if (r == ep * 8u - 1u)
        __hip_atomic_store(bar + 288, ep, __ATOMIC_RELAXED, AGENT);
    }
    while (__hip_atomic_load(bar + 288, __ATOMIC_RELAXED, AGENT) < ep)
      __builtin_amdgcn_s_sleep(2);
  }
  __syncthreads();
}

// LDS (114KB) already caps the CU at 1 block = 16 waves = 4 waves/EU.
// Force the register allocator to plan for exactly that (128-VGPR budget)
// so the 48 pinned weight VGPRs are actually allocatable.
__global__ __launch_bounds__(GTHR)
__attribute__((amdgpu_waves_per_eu(4, 4))) void k_main(
    const _Float16* __restrict__ Wvh, const _Float16* __restrict__ Woh,
    const _Float16* __restrict__ fc1h, const float* __restrict__ fc1b,
    const _Float16* __restrict__ fc2h, const float* __restrict__ fc2b,
    const float* __restrict__ lng, const float* __restrict__ lnb,
    const float* __restrict__ lzg, const float* __restrict__ lzb,
    float* __restrict__ S, float* __restrict__ ocum,
    float* __restrict__ Smir, float* __restrict__ Omir, float* __restrict__ vmir,
    _Float16* __restrict__ hmir, unsigned* __restrict__ bar) {
  __shared__ __align__(16) _Float16 fc1L[16 * MDIM];   // 32KB, rows b*16..+15
  __shared__ __align__(16) _Float16 fc2L[4 * H4];      // 32KB, rows b*4..+3
  __shared__ __align__(16) _Float16 zxL[2 * TKL * MDIM];  // 40KB: zL | x2L; phase-B hL reuses
  __shared__ __align__(16) _Float16 vstL[3 * MDIM];    // 6KB
  __shared__ __align__(16) float4 stats[TKL];
  __shared__ __align__(16) float vgs[3][16];
  __shared__ __align__(16) _Float16 hgelL2[TKL][16];
  __shared__ float part[4][4][TKL];
  __shared__ __align__(16) float sOut[TKL][4];
  _Float16* zL = zxL;
  _Float16* x2L = zxL + TKL * MDIM;
  _Float16* hL = zxL;  // phase-B reuse (5*4096 = 20480 elems)

  const int tid = threadIdx.x;
  const int lane = tid & 63;
  const int bwave = tid >> 6;
  const int b = blockIdx.x;
  unsigned ep = 0;

  __builtin_amdgcn_fence(__ATOMIC_ACQUIRE, "agent");

  // ---- pin Wv/Wo rows in registers: group g = b + 256r, row (g&63)*16 + bwave ----
  int aR[3], rgR[3];
  bool okR[3];
  U16 wv[3][2], wo[3][2];
#pragma unroll
  for (int r = 0; r < 3; ++r) {
    const int g = b + (r << 8);
    okR[r] = g < 640;
    aR[r] = g >> 6;
    rgR[r] = g & 63;
    if (okR[r]) {
      const size_t off = ((size_t)aR[r] << 20) + ((size_t)((rgR[r] << 4) | bwave) << 10);
      wv[r][0].u = *(const uv4*)(Wvh + off + (lane << 3));
      wv[r][1].u = *(const uv4*)(Wvh + off + 512 + (lane << 3));
      wo[r][0].u = *(const uv4*)(Woh + off + (lane << 3));
      wo[r][1].u = *(const uv4*)(Woh + off + 512 + (lane << 3));
    } else {
      wv[r][0].u = uv4{0, 0, 0, 0}; wv[r][1].u = uv4{0, 0, 0, 0};
      wo[r][0].u = uv4{0, 0, 0, 0}; wo[r][1].u = uv4{0, 0, 0, 0};
    }
  }
  // ---- persist fc1 (16 rows) and fc2 (4 rows) in LDS ----
  {
    const _Float16* s1 = fc1h + (size_t)b * 16384;
    const _Float16* s2 = fc2h + (size_t)b * 16384;
#pragma unroll
    for (int r = 0; r < 2; ++r) {
      const int s = tid + (r << 10);
      *(uv4*)(fc1L + (s << 3)) = *(const uv4*)(s1 + (s << 3));
      *(uv4*)(fc2L + (s << 3)) = *(const uv4*)(s2 + (s << 3));
    }
  }
  __syncthreads();

  for (int t = 0; t < NWFR; ++t) {
    // keep-alive: "+v" marks the weight fragments as asm-modified, making
    // rematerialization-by-reload illegal -> they MUST stay in VGPRs.
#pragma unroll
    for (int r = 0; r < 3; ++r)
      asm volatile("" : "+v"(wv[r][0].u), "+v"(wv[r][1].u),
                        "+v"(wo[r][0].u), "+v"(wo[r][1].u));

    const int alo = (t - (NT - 1)) > 0 ? (t - (NT - 1)) : 0;
    const int ahi = t < (TKL - 1) ? t : (TKL - 1);
    const int nc = ahi - alo + 1;
    const float* Smirt = Smir + (size_t)t * NT * MDIM;
    const float* Omirt = Omir + (size_t)t * TKL * MDIM;
    bool actR[3];
#pragma unroll
    for (int r = 0; r < 3; ++r)
      actR[r] = okR[r] && aR[r] >= alo && aR[r] <= ahi && (t - aR[r]) != NT - 1;

    // ---- LN stats: one wave per cell, 16 contiguous f32 per lane ----
    if (bwave < nc) {
      const int a = alo + bwave, i = t - a;
      const fv4* sp = (const fv4*)(Smirt + (size_t)i * MDIM + (lane << 4));
      const fv4* op = (const fv4*)(Omirt + (size_t)a * MDIM + (lane << 4));
      fv4 sv[4], tv[4];
#pragma unroll
      for (int k = 0; k < 4; ++k) { sv[k] = sp[k]; tv[k] = sv[k] + op[k]; }
      float s1 = 0.f, t1 = 0.f;
#pragma unroll
      for (int k = 0; k < 4; ++k)
#pragma unroll
        for (int e = 0; e < 4; ++e) { s1 += sv[k][e]; t1 += tv[k][e]; }
      const float mu_s = wred(s1) * (1.0f / MDIM);
      const float mu_t = wred(t1) * (1.0f / MDIM);
      float s2 = 0.f, t2 = 0.f;
#pragma unroll
      for (int k = 0; k < 4; ++k)
#pragma unroll
        for (int e = 0; e < 4; ++e) {
          float d = sv[k][e] - mu_s; s2 += d * d;
          float f = tv[k][e] - mu_t; t2 += f * f;
        }
      const float var_s = wred(s2) * (1.0f / MDIM);
      const float var_t = wred(t2) * (1.0f / MDIM);
      if (!lane)
        stats[bwave] = make_float4(mu_s, rsqrtf(var_s + 1e-5f),
                                   mu_t, rsqrtf(var_t + 1e-5f));
    }
    __syncthreads();

    // ---- elementwise z/x2 into LDS: 8 cells per pass, 128 threads/cell ----
#pragma unroll
    for (int p = 0; p < 2; ++p) {
      const int c = (p << 3) + (tid >> 7);
      if (c < nc) {
        const int a = alo + c, i = t - a;
        const int e = (tid & 127) << 3;
        const float4 st4 = stats[c];
        fv4 sA = *(const fv4*)(Smirt + (size_t)i * MDIM + e);
        fv4 sB = *(const fv4*)(Smirt + (size_t)i * MDIM + e + 4);
        fv4 oA = *(const fv4*)(Omirt + (size_t)a * MDIM + e);
        fv4 oB = *(const fv4*)(Omirt + (size_t)a * MDIM + e + 4);
        fv4 g1A = *(const fv4*)(lng + e), g1B = *(const fv4*)(lng + e + 4);
        fv4 b1A = *(const fv4*)(lnb + e), b1B = *(const fv4*)(lnb + e + 4);
        fv4 g2A = *(const fv4*)(lzg + e), g2B = *(const fv4*)(lzg + e + 4);
        fv4 b2A = *(const fv4*)(lzb + e), b2B = *(const fv4*)(lzb + e + 4);
        U16 zz, xx;
#pragma unroll
        for (int k = 0; k < 4; ++k) {
          zz.f[k] = (_Float16)((sA[k] - st4.x) * st4.y * g1A[k] + b1A[k]);
          zz.f[4 + k] = (_Float16)((sB[k] - st4.x) * st4.y * g1B[k] + b1B[k]);
          const float u0 = sA[k] + oA[k], u1 = sB[k] + oB[k];
          xx.f[k] = (_Float16)((u0 - st4.z) * st4.w * g2A[k] + b2A[k] + u0);
          xx.f[4 + k] = (_Float16)((u1 - st4.z) * st4.w * g2B[k] + b2B[k] + u1);
        }
        *(uv4*)(zL + c * MDIM + e) = zz.u;
        *(uv4*)(x2L + c * MDIM + e) = xx.u;
      }
    }
    __syncthreads();

    // ---- Phase A: Wv from registers; fc1 from LDS ----
#pragma unroll
    for (int r = 0; r < 3; ++r)
      if (actR[r]) {
        const int c = aR[r] - alo;
        U16 z0, z1;
        z0.u = *(const uv4*)(zL + c * MDIM + (lane << 3));
        z1.u = *(const uv4*)(zL + c * MDIM + 512 + (lane << 3));
        float acc = dot16(wv[r][0], z0, 0.f);
        acc = dot16(wv[r][1], z1, acc);
        acc = wred(acc);
        if (!lane) vgs[r][bwave] = acc;
      }
    {
      U16 f0, f1;
      f0.u = *(const uv4*)(fc1L + bwave * MDIM + (lane << 3));
      f1.u = *(const uv4*)(fc1L + bwave * MDIM + 512 + (lane << 3));
      const float bias = fc1b[(b << 4) | bwave];
      float sel = 0.f;
#pragma unroll
      for (int c = 0; c < TKL; ++c)
        if (c < nc) {
          U16 x0, x1;
          x0.u = *(const uv4*)(x2L + c * MDIM + (lane << 3));
          x1.u = *(const uv4*)(x2L + c * MDIM + 512 + (lane << 3));
          float acc = dot16(f0, x0, 0.f);
          acc = dot16(f1, x1, acc);
          acc = wred(acc);
          sel = (lane == c) ? acc : sel;
        }
      const float xg = sel + bias;
      const float ge = 0.5f * xg * (1.0f + erff(xg * 0.70710678118654752f));
      if (lane < nc) hgelL2[lane][bwave] = (_Float16)ge;
    }
    __syncthreads();
    // packed mirror stores: h (16B x2 per cell), v (16B x4 per group)
    if (bwave < nc && lane < 2) {
      uv4 hv = *(const uv4*)(&hgelL2[bwave][lane << 3]);
      stg16(hmir + ((size_t)t * TKL + alo + bwave) * H4 + (b << 4) + (lane << 3), hv);
    }
    if (bwave >= 13 && lane < 4) {
      const int r = bwave - 13;
      if (actR[r]) {
        fv4 vv = *(const fv4*)(&vgs[r][lane << 2]);
        stg16(vmir + ((size_t)t * TKL + aR[r]) * MDIM + (rgR[r] << 4) + (lane << 2),
              __builtin_bit_cast(uv4, vv));
      }
    }
    ++ep; gbar(bar, ep);

    // ---- Phase B: stage v rows + h chunk0 ----
    {
      const int r = tid >> 8, e = (tid & 255) << 2;
      if (r < 3 && actR[r]) {
        fv4 v = *(const fv4*)(vmir + ((size_t)t * TKL + aR[r]) * MDIM + e);
        vstL[(r << 10) + e] = (_Float16)v[0];
        vstL[(r << 10) + e + 1] = (_Float16)v[1];
        vstL[(r << 10) + e + 2] = (_Float16)v[2];
        vstL[(r << 10) + e + 3] = (_Float16)v[3];
      }
    }
#pragma unroll
    for (int rr = 0; rr < 3; ++rr) {
      const int s = tid + (rr << 10);
      if (s < 2560) {
        const int q = s >> 9, idx = (s & 511) << 3;
        if (q < nc)
          *(uv4*)(hL + q * H4 + idx) =
              *(const uv4*)(hmir + ((size_t)t * TKL + alo + q) * H4 + idx);
      }
    }
    __syncthreads();

    // ---- Wo from registers + fc2 chunk0 ----
#pragma unroll
    for (int r = 0; r < 3; ++r)
      if (actR[r]) {
        U16 v0, v1;
        v0.u = *(const uv4*)(vstL + (r << 10) + (lane << 3));
        v1.u = *(const uv4*)(vstL + (r << 10) + 512 + (lane << 3));
        float acc = dot16(wo[r][0], v0, 0.f);
        acc = dot16(wo[r][1], v1, acc);
        acc = wred(acc);
        if (!lane) vgs[r][bwave] = acc;
      }
    const int rl = bwave >> 2, kq = bwave & 3;
    U16 w0, w1;
    w0.u = *(const uv4*)(fc2L + rl * H4 + (kq << 10) + (lane << 3));
    w1.u = *(const uv4*)(fc2L + rl * H4 + (kq << 10) + 512 + (lane << 3));
#pragma unroll
    for (int q = 0; q < 5; ++q)
      if (q < nc) {
        U16 h0, h1;
        h0.u = *(const uv4*)(hL + q * H4 + (kq << 10) + (lane << 3));
        h1.u = *(const uv4*)(hL + q * H4 + (kq << 10) + 512 + (lane << 3));
        float acc = dot16(w0, h0, 0.f);
        acc = dot16(w1, h1, acc);
        acc = wred(acc);
        if (!lane) part[rl][kq][q] = acc;
      }
    __syncthreads();

    // ---- ocum RMW (plain cached, block-exclusive) + Omir write-through; stage h chunk1 ----
    if (bwave >= 13 && lane < 4) {
      const int r = bwave - 13;
      if (actR[r]) {
        const int R = (rgR[r] << 4) + (lane << 2);
        float* po = ocum + aR[r] * MDIM + R;
        fv4 old = *(const fv4*)po;
        fv4 nv = old + *(const fv4*)(&vgs[r][lane << 2]);
        *(fv4*)po = nv;
        stg16(Omir + ((size_t)(t + 1) * TKL + aR[r]) * MDIM + R,
              __builtin_bit_cast(uv4, nv));
      }
    }
#pragma unroll
    for (int rr = 0; rr < 3; ++rr) {
      const int s = tid + (rr << 10);
      if (s < 2560) {
        const int q = s >> 9, idx = (s & 511) << 3;
        const int c = 5 + q;
        if (c < nc)
          *(uv4*)(hL + q * H4 + idx) =
              *(const uv4*)(hmir + ((size_t)t * TKL + alo + c) * H4 + idx);
      }
    }
    __syncthreads();

    // ---- fc2 chunk1 ----
#pragma unroll
    for (int q = 0; q < 5; ++q) {
      const int c = 5 + q;
      if (c < nc) {
        U16 h0, h1;
        h0.u = *(const uv4*)(hL + q * H4 + (kq << 10) + (lane << 3));
        h1.u = *(const uv4*)(hL + q * H4 + (kq << 10) + 512 + (lane << 3));
        float acc = dot16(w0, h0, 0.f);
        acc = dot16(w1, h1, acc);
        acc = wred(acc);
        if (!lane) part[rl][kq][c] = acc;
      }
    }
    __syncthreads();

    // ---- fc2 epilogue: sum quarters, write S (a==9) or Smir(t+1) ----
    if (bwave < nc && lane < 4)
      sOut[bwave][lane] = part[lane][0][bwave] + part[lane][1][bwave] +
                          part[lane][2][bwave] + part[lane][3][bwave] +
                          fc2b[(b << 2) | lane];
    __syncthreads();
    if (bwave < nc && !lane) {
      const int a = alo + bwave, i = t - a;
      fv4 sv = *(const fv4*)(&sOut[bwave][0]);
      if (a == TKL - 1)
        *(fv4*)(S + (size_t)i * MDIM + (b << 2)) = sv;
      else
        stg16(Smir + ((size_t)(t + 1) * NT + i) * MDIM + (b << 2),
              __builtin_bit_cast(uv4, sv));
    }
    ++ep; gbar(bar, ep);
  }
}

extern "C" void kernel_launch(void* const* d_in, const int* in_sizes, int n_in,
                              void* d_out, int out_size, void* d_ws, size_t ws_size,
                              hipStream_t stream) {
  const float* x    = (const float*)d_in[0];
  const float* W    = (const float*)d_in[1];
  const float* Wv   = (const float*)d_in[4];
  const float* Wo   = (const float*)d_in[5];
  const float* lng  = (const float*)d_in[6];
  const float* lnb  = (const float*)d_in[7];
  const float* lzg  = (const float*)d_in[8];
  const float* lzb  = (const float*)d_in[9];
  const float* fc1w = (const float*)d_in[10];
  const float* fc1b = (const float*)d_in[11];
  const float* fc2w = (const float*)d_in[12];
  const float* fc2b = (const float*)d_in[13];
  float* S = (float*)d_out;

  float* xcf  = (float*)d_ws;                 // 30720 f32
  float* ocum = xcf + 30720;                  // 10240 f32
  unsigned* bar = (unsigned*)(ocum + 10240);  // 512 u32
  float* Smir = (float*)(bar + 512);          // 40*30*1024 f32
  float* Omir = Smir + 1228800;               // 40*10*1024 f32
  float* vmir = Omir + 409600;                // 40*10*1024 f32
  _Float16* hmir = (_Float16*)(vmir + 409600);  // 40*10*4096 f16
  _Float16* Wvh  = hmir + 1638400;
  _Float16* Woh  = Wvh + 10485760;
  _Float16* fc1h = Woh + 10485760;
  _Float16* fc2h = fc1h + 4194304;

  hipLaunchKernelGGL(k_cvt, dim3(5120), dim3(256), 0, stream, Wv, Wvh, 1310720);
  hipLaunchKernelGGL(k_cvt, dim3(5120), dim3(256), 0, stream, Wo, Woh, 1310720);
  hipLaunchKernelGGL(k_cvt, dim3(2048), dim3(256), 0, stream, fc1w, fc1h, 524288);
  hipLaunchKernelGGL(k_cvt, dim3(2048), dim3(256), 0, stream, fc2w, fc2h, 524288);
  hipLaunchKernelGGL(k_xcf, dim3((NT * MDIM + 255) / 256), dim3(256), 0, stream, x, xcf);
  hipLaunchKernelGGL(k_s0, dim3(NT * MDIM / 4), dim3(256), 0, stream, xcf, W, S, Smir);
  hipMemsetAsync(ocum, 0, 10240 * sizeof(float), stream);
  hipMemsetAsync(Omir, 0, 409600 * sizeof(float), stream);
  hipMemsetAsync(bar, 0, 2048, stream);

  void* args[] = {(void*)&Wvh, (void*)&Woh, (void*)&fc1h, (void*)&fc1b,
                  (void*)&fc2h, (void*)&fc2b, (void*)&lng, (void*)&lnb,
                  (void*)&lzg, (void*)&lzb, (void*)&S,   (void*)&ocum,
                  (void*)&Smir, (void*)&Omir, (void*)&vmir, (void*)&hmir,
                  (void*)&bar};
  hipLaunchCooperativeKernel((void*)k_main, dim3(GBLK), dim3(GTHR), args, 0, stream);
}

// Round 10
// 1019.914 us; speedup vs baseline: 1.1243x; 1.1243x over previous
//
#include <hip/hip_runtime.h>

#define MDIM 1024
#define H4   4096
#define TKL  10
#define NT   30
#define NWFR 39
#define GBLK 256
#define GTHR 1024
#define AGENT __HIP_MEMORY_SCOPE_AGENT

typedef _Float16 h2v __attribute__((ext_vector_type(2)));
typedef unsigned int uv4 __attribute__((ext_vector_type(4)));
typedef float fv4 __attribute__((ext_vector_type(4)));
union U16 { uv4 u; h2v h[4]; _Float16 f[8]; };

__device__ __forceinline__ float wred(float v) {
#pragma unroll
  for (int o = 32; o; o >>= 1) v += __shfl_xor(v, o, 64);
  return v;
}

__device__ __forceinline__ float dot16(const U16& w, const U16& x, float acc) {
  acc = __builtin_amdgcn_fdot2(w.h[0], x.h[0], acc, false);
  acc = __builtin_amdgcn_fdot2(w.h[1], x.h[1], acc, false);
  acc = __builtin_amdgcn_fdot2(w.h[2], x.h[2], acc, false);
  acc = __builtin_amdgcn_fdot2(w.h[3], x.h[3], acc, false);
  return acc;
}

// write-through 16B store (stays visible at coherence point, never dirty in L2)
__device__ __forceinline__ void stg16(const void* p, uv4 v) {
  asm volatile("global_store_dwordx4 %0, %1, off sc0 sc1" :: "v"(p), "v"(v) : "memory");
}

__global__ void k_cvt(const float* __restrict__ in, _Float16* __restrict__ out, int n8) {
  int g = blockIdx.x * blockDim.x + threadIdx.x;
  if (g >= n8) return;
  const float4* p = (const float4*)in;
  float4 a = p[2 * g], b = p[2 * g + 1];
  U16 o;
  o.f[0] = (_Float16)a.x; o.f[1] = (_Float16)a.y;
  o.f[2] = (_Float16)a.z; o.f[3] = (_Float16)a.w;
  o.f[4] = (_Float16)b.x; o.f[5] = (_Float16)b.y;
  o.f[6] = (_Float16)b.z; o.f[7] = (_Float16)b.w;
  ((uv4*)out)[g] = o.u;
}

__global__ void k_xcf(const float* __restrict__ x, float* __restrict__ xcf) {
  int idx = blockIdx.x * blockDim.x + threadIdx.x;
  if (idx >= NT * MDIM) return;
  int i = idx >> 10, m = idx & (MDIM - 1);
  int c = m & 31, s = m >> 5;
  const float* p = x + c * (32 * 360) + s * 360 + i * 12;
  float acc = 0.f;
#pragma unroll
  for (int k = 0; k < 12; ++k) acc += p[k];
  xcf[idx] = acc * (1.0f / 12.0f);
}

__global__ void k_s0(const float* __restrict__ xcf, const float* __restrict__ W,
                     float* __restrict__ S, float* __restrict__ Smir) {
  int wid = (blockIdx.x * blockDim.x + threadIdx.x) >> 6;
  int lane = threadIdx.x & 63;
  if (wid >= NT * MDIM) return;
  int i = wid >> 10, m = wid & (MDIM - 1);
  const float4* wr = (const float4*)(W + (size_t)m * MDIM);
  const float4* xr = (const float4*)(xcf + i * MDIM);
  float acc = 0.f;
#pragma unroll
  for (int k = 0; k < 4; ++k) {
    float4 w = wr[lane + (k << 6)];
    float4 xv = xr[lane + (k << 6)];
    acc += w.x * xv.x + w.y * xv.y + w.z * xv.z + w.w * xv.w;
  }
  acc = wred(acc);
  if (lane == 0) {
    int e = m & ~1;
    float ang = (float)i / powf(10000.0f, (float)e / 512.0f);
    float pe = (m & 1) ? cosf(ang) : sinf(ang);
    float val = acc + pe;
    S[wid] = val;
    Smir[((size_t)i * NT + i) * MDIM + m] = val;
  }
}

// two-level fence-free barrier (proven R4..R9)
__device__ __forceinline__ void gbar(unsigned* bar, unsigned ep) {
  asm volatile("s_waitcnt vmcnt(0)" ::: "memory");
  __syncthreads();
  if (threadIdx.x == 0) {
    unsigned* leaf = bar + ((blockIdx.x & 7) << 5);
    const unsigned prev = __hip_atomic_fetch_add(leaf, 1u, __ATOMIC_RELAXED, AGENT);
    if (prev == ep * 32u - 1u) {
      const unsigned r = __hip_atomic_fetch_add(bar + 256, 1u, __ATOMIC_RELAXED, AGENT);
      if (r == ep * 8u - 1u)
        __hip_atomic_store(bar + 288, ep, __ATOMIC_RELAXED, AGENT);
    }
    while (__hip_atomic_load(bar + 288, __ATOMIC_RELAXED, AGENT) < ep)
      __builtin_amdgcn_s_sleep(2);
  }
  __syncthreads();
}

__global__ __launch_bounds__(GTHR) void k_main(
    const _Float16* __restrict__ Wvh, const _Float16* __restrict__ Woh,
    const _Float16* __restrict__ fc1h, const float* __restrict__ fc1b,
    const _Float16* __restrict__ fc2h, const float* __restrict__ fc2b,
    const float* __restrict__ lng, const float* __restrict__ lnb,
    const float* __restrict__ lzg, const float* __restrict__ lzb,
    float* __restrict__ S, float* __restrict__ ocum,
    float* __restrict__ Smir, float* __restrict__ Omir, float* __restrict__ vmir,
    _Float16* __restrict__ hmir, unsigned* __restrict__ bar) {
  // LDS: fc1 32KB + Wo (3 groups) 96KB + x2 20KB (h-chunks reuse) + zv 6KB = 154KB
  __shared__ __align__(16) _Float16 fc1L[16 * MDIM];
  __shared__ __align__(16) _Float16 WoL[3 * 16 * MDIM];
  __shared__ __align__(16) _Float16 x2L[TKL * MDIM];
  __shared__ __align__(16) _Float16 zvL[3 * MDIM];
  __shared__ __align__(16) float4 stats[TKL];
  __shared__ __align__(16) float vgs[3][16];
  __shared__ __align__(16) _Float16 hgelL2[TKL][16];
  __shared__ float part[4][4][TKL];
  __shared__ __align__(16) float sOut[TKL][4];
  _Float16* hL = x2L;  // phase-B 2-cell h chunks (16KB of 20KB)

  const int tid = threadIdx.x;
  const int lane = tid & 63;
  const int bwave = tid >> 6;
  const int b = blockIdx.x;
  unsigned ep = 0;

  __builtin_amdgcn_fence(__ATOMIC_ACQUIRE, "agent");

  // group assignment: g = b + 256r -> (a, rowgroup)
  int aR[3], rgR[3];
  bool okR[3];
#pragma unroll
  for (int r = 0; r < 3; ++r) {
    const int g = b + (r << 8);
    okR[r] = g < 640;
    aR[r] = g >> 6;
    rgR[r] = g & 63;
  }
  // prologue: fc1 rows (b*16..+15) and Wo groups into LDS
  {
    const _Float16* s1 = fc1h + (size_t)b * 16384;
#pragma unroll
    for (int r = 0; r < 2; ++r) {
      const int s = tid + (r << 10);
      *(uv4*)(fc1L + (s << 3)) = *(const uv4*)(s1 + (s << 3));
    }
#pragma unroll
    for (int r = 0; r < 3; ++r)
      if (okR[r]) {
        const _Float16* src = Woh + ((size_t)aR[r] << 20) + ((size_t)rgR[r] << 14);
#pragma unroll
        for (int it = 0; it < 2; ++it) {
          const int s = tid + (it << 10);
          *(uv4*)(WoL + r * 16384 + (s << 3)) = *(const uv4*)(src + (s << 3));
        }
      }
  }
  __syncthreads();

  for (int t = 0; t < NWFR; ++t) {
    const int alo = (t - (NT - 1)) > 0 ? (t - (NT - 1)) : 0;
    const int ahi = t < (TKL - 1) ? t : (TKL - 1);
    const int nc = ahi - alo + 1;
    const float* Smirt = Smir + (size_t)t * NT * MDIM;
    const float* Omirt = Omir + (size_t)t * TKL * MDIM;
    bool actR[3];
    int cz[3];
#pragma unroll
    for (int r = 0; r < 3; ++r) {
      actR[r] = okR[r] && aR[r] >= alo && aR[r] <= ahi && (t - aR[r]) != NT - 1;
      cz[r] = actR[r] ? (aR[r] - alo) : -1;
    }

    // ---- LN stats: one wave per cell ----
    if (bwave < nc) {
      const int a = alo + bwave, i = t - a;
      const fv4* sp = (const fv4*)(Smirt + (size_t)i * MDIM + (lane << 4));
      const fv4* op = (const fv4*)(Omirt + (size_t)a * MDIM + (lane << 4));
      fv4 sv[4], tv[4];
#pragma unroll
      for (int k = 0; k < 4; ++k) { sv[k] = sp[k]; tv[k] = sv[k] + op[k]; }
      float s1 = 0.f, t1 = 0.f;
#pragma unroll
      for (int k = 0; k < 4; ++k)
#pragma unroll
        for (int e = 0; e < 4; ++e) { s1 += sv[k][e]; t1 += tv[k][e]; }
      const float mu_s = wred(s1) * (1.0f / MDIM);
      const float mu_t = wred(t1) * (1.0f / MDIM);
      float s2 = 0.f, t2 = 0.f;
#pragma unroll
      for (int k = 0; k < 4; ++k)
#pragma unroll
        for (int e = 0; e < 4; ++e) {
          float d = sv[k][e] - mu_s; s2 += d * d;
          float f = tv[k][e] - mu_t; t2 += f * f;
        }
      const float var_s = wred(s2) * (1.0f / MDIM);
      const float var_t = wred(t2) * (1.0f / MDIM);
      if (!lane)
        stats[bwave] = make_float4(mu_s, rsqrtf(var_s + 1e-5f),
                                   mu_t, rsqrtf(var_t + 1e-5f));
    }
    __syncthreads();

    // ---- elementwise: x2 for all cells; z only for this block's 3 cells ----
#pragma unroll
    for (int p = 0; p < 2; ++p) {
      const int c = (p << 3) + (tid >> 7);
      if (c < nc) {
        const int a = alo + c, i = t - a;
        const int e = (tid & 127) << 3;
        const float4 st4 = stats[c];
        fv4 sA = *(const fv4*)(Smirt + (size_t)i * MDIM + e);
        fv4 sB = *(const fv4*)(Smirt + (size_t)i * MDIM + e + 4);
        fv4 oA = *(const fv4*)(Omirt + (size_t)a * MDIM + e);
        fv4 oB = *(const fv4*)(Omirt + (size_t)a * MDIM + e + 4);
        fv4 g1A = *(const fv4*)(lng + e), g1B = *(const fv4*)(lng + e + 4);
        fv4 b1A = *(const fv4*)(lnb + e), b1B = *(const fv4*)(lnb + e + 4);
        fv4 g2A = *(const fv4*)(lzg + e), g2B = *(const fv4*)(lzg + e + 4);
        fv4 b2A = *(const fv4*)(lzb + e), b2B = *(const fv4*)(lzb + e + 4);
        U16 zz, xx;
#pragma unroll
        for (int k = 0; k < 4; ++k) {
          zz.f[k] = (_Float16)((sA[k] - st4.x) * st4.y * g1A[k] + b1A[k]);
          zz.f[4 + k] = (_Float16)((sB[k] - st4.x) * st4.y * g1B[k] + b1B[k]);
          const float u0 = sA[k] + oA[k], u1 = sB[k] + oB[k];
          xx.f[k] = (_Float16)((u0 - st4.z) * st4.w * g2A[k] + b2A[k] + u0);
          xx.f[4 + k] = (_Float16)((u1 - st4.z) * st4.w * g2B[k] + b2B[k] + u1);
        }
        *(uv4*)(x2L + c * MDIM + e) = xx.u;
        if (c == cz[0]) *(uv4*)(zvL + e) = zz.u;
        if (c == cz[1]) *(uv4*)(zvL + MDIM + e) = zz.u;
        if (c == cz[2]) *(uv4*)(zvL + 2 * MDIM + e) = zz.u;
      }
    }
    __syncthreads();

    // ---- Phase A: Wv (L2-streamed, z from zvL) + fc1 (LDS) ----
#pragma unroll
    for (int r = 0; r < 3; ++r)
      if (actR[r]) {
        const _Float16* wp =
            Wvh + ((size_t)aR[r] << 20) + ((size_t)((rgR[r] << 4) | bwave) << 10);
        U16 w0, w1, z0, z1;
        w0.u = *(const uv4*)(wp + (lane << 3));
        w1.u = *(const uv4*)(wp + 512 + (lane << 3));
        z0.u = *(const uv4*)(zvL + r * MDIM + (lane << 3));
        z1.u = *(const uv4*)(zvL + r * MDIM + 512 + (lane << 3));
        float acc = dot16(w0, z0, 0.f);
        acc = dot16(w1, z1, acc);
        acc = wred(acc);
        if (!lane) vgs[r][bwave] = acc;
      }
    {
      U16 f0, f1;
      f0.u = *(const uv4*)(fc1L + bwave * MDIM + (lane << 3));
      f1.u = *(const uv4*)(fc1L + bwave * MDIM + 512 + (lane << 3));
      const float bias = fc1b[(b << 4) | bwave];
      float sel = 0.f;
#pragma unroll
      for (int c = 0; c < TKL; ++c)
        if (c < nc) {
          U16 x0, x1;
          x0.u = *(const uv4*)(x2L + c * MDIM + (lane << 3));
          x1.u = *(const uv4*)(x2L + c * MDIM + 512 + (lane << 3));
          float acc = dot16(f0, x0, 0.f);
          acc = dot16(f1, x1, acc);
          acc = wred(acc);
          sel = (lane == c) ? acc : sel;
        }
      const float xg = sel + bias;
      const float ge = 0.5f * xg * (1.0f + erff(xg * 0.70710678118654752f));
      if (lane < nc) hgelL2[lane][bwave] = (_Float16)ge;
    }
    __syncthreads();
    // packed mirror stores
    if (bwave < nc && lane < 2) {
      uv4 hv = *(const uv4*)(&hgelL2[bwave][lane << 3]);
      stg16(hmir + ((size_t)t * TKL + alo + bwave) * H4 + (b << 4) + (lane << 3), hv);
    }
    if (bwave >= 13 && lane < 4) {
      const int r = bwave - 13;
      if (actR[r]) {
        fv4 vv = *(const fv4*)(&vgs[r][lane << 2]);
        stg16(vmir + ((size_t)t * TKL + aR[r]) * MDIM + (rgR[r] << 4) + (lane << 2),
              __builtin_bit_cast(uv4, vv));
      }
    }
    ++ep; gbar(bar, ep);

    // ---- Phase B ----
    // fc2 quarter-row for this wave (L2-resident, held in regs across chunks)
    const int rl = bwave >> 2, kq = bwave & 3;
    U16 w2a, w2b;
    {
      const _Float16* fp = fc2h + ((size_t)((b << 2) | rl) << 12) + (kq << 10);
      w2a.u = *(const uv4*)(fp + (lane << 3));
      w2b.u = *(const uv4*)(fp + 512 + (lane << 3));
    }
    // stage v rows (zvL reuse) + h chunk0 (cells 0,1)
    {
      const int r = tid >> 8, e4 = (tid & 255) << 2;
      if (r < 3 && actR[r]) {
        fv4 v = *(const fv4*)(vmir + ((size_t)t * TKL + aR[r]) * MDIM + e4);
        zvL[r * MDIM + e4] = (_Float16)v[0];
        zvL[r * MDIM + e4 + 1] = (_Float16)v[1];
        zvL[r * MDIM + e4 + 2] = (_Float16)v[2];
        zvL[r * MDIM + e4 + 3] = (_Float16)v[3];
      }
      const int q = tid >> 9, idx = (tid & 511) << 3;
      if (q < nc)
        *(uv4*)(hL + q * H4 + idx) =
            *(const uv4*)(hmir + ((size_t)t * TKL + alo + q) * H4 + idx);
    }
    __syncthreads();
    // Wo dots (weights + v both from LDS)
#pragma unroll
    for (int r = 0; r < 3; ++r)
      if (actR[r]) {
        U16 w0, w1, v0, v1;
        w0.u = *(const uv4*)(WoL + r * 16384 + bwave * MDIM + (lane << 3));
        w1.u = *(const uv4*)(WoL + r * 16384 + bwave * MDIM + 512 + (lane << 3));
        v0.u = *(const uv4*)(zvL + r * MDIM + (lane << 3));
        v1.u = *(const uv4*)(zvL + r * MDIM + 512 + (lane << 3));
        float acc = dot16(w0, v0, 0.f);
        acc = dot16(w1, v1, acc);
        acc = wred(acc);
        if (!lane) vgs[r][bwave] = acc;
      }
    // fc2 chunk0 (cells 0,1)
#pragma unroll
    for (int q = 0; q < 2; ++q)
      if (q < nc) {
        U16 h0, h1;
        h0.u = *(const uv4*)(hL + q * H4 + (kq << 10) + (lane << 3));
        h1.u = *(const uv4*)(hL + q * H4 + (kq << 10) + 512 + (lane << 3));
        float acc = dot16(w2a, h0, 0.f);
        acc = dot16(w2b, h1, acc);
        acc = wred(acc);
        if (!lane) part[rl][kq][q] = acc;
      }
    __syncthreads();
    // ocum RMW (plain cached, block-exclusive) + Omir write-through
    if (bwave >= 13 && lane < 4) {
      const int r = bwave - 13;
      if (actR[r]) {
        const int R = (rgR[r] << 4) + (lane << 2);
        float* po = ocum + aR[r] * MDIM + R;
        fv4 old = *(const fv4*)po;
        fv4 nv = old + *(const fv4*)(&vgs[r][lane << 2]);
        *(fv4*)po = nv;
        stg16(Omir + ((size_t)(t + 1) * TKL + aR[r]) * MDIM + R,
              __builtin_bit_cast(uv4, nv));
      }
    }
    // remaining fc2 chunks (cells 2..9, two at a time through hL)
    for (int ch = 1; ch < 5; ++ch) {
      const int c0 = ch << 1;
      if (c0 >= nc) break;  // uniform across grid
      {
        const int q = tid >> 9, idx = (tid & 511) << 3;
        const int c = c0 + q;
        if (c < nc)
          *(uv4*)(hL + q * H4 + idx) =
              *(const uv4*)(hmir + ((size_t)t * TKL + alo + c) * H4 + idx);
      }
      __syncthreads();
#pragma unroll
      for (int q = 0; q < 2; ++q) {
        const int c = c0 + q;
        if (c < nc) {
          U16 h0, h1;
          h0.u = *(const uv4*)(hL + q * H4 + (kq << 10) + (lane << 3));
          h1.u = *(const uv4*)(hL + q * H4 + (kq << 10) + 512 + (lane << 3));
          float acc = dot16(w2a, h0, 0.f);
          acc = dot16(w2b, h1, acc);
          acc = wred(acc);
          if (!lane) part[rl][kq][c] = acc;
        }
      }
      __syncthreads();
    }

    // ---- fc2 epilogue: sum quarters, write S (a==9) or Smir(t+1) ----
    if (bwave < nc && lane < 4)
      sOut[bwave][lane] = part[lane][0][bwave] + part[lane][1][bwave] +
                          part[lane][2][bwave] + part[lane][3][bwave] +
                          fc2b[(b << 2) | lane];
    __syncthreads();
    if (bwave < nc && !lane) {
      const int a = alo + bwave, i = t - a;
      fv4 sv = *(const fv4*)(&sOut[bwave][0]);
      if (a == TKL - 1)
        *(fv4*)(S + (size_t)i * MDIM + (b << 2)) = sv;
      else
        stg16(Smir + ((size_t)(t + 1) * NT + i) * MDIM + (b << 2),
              __builtin_bit_cast(uv4, sv));
    }
    ++ep; gbar(bar, ep);
  }
}

extern "C" void kernel_launch(void* const* d_in, const int* in_sizes, int n_in,
                              void* d_out, int out_size, void* d_ws, size_t ws_size,
                              hipStream_t stream) {
  const float* x    = (const float*)d_in[0];
  const float* W    = (const float*)d_in[1];
  const float* Wv   = (const float*)d_in[4];
  const float* Wo   = (const float*)d_in[5];
  const float* lng  = (const float*)d_in[6];
  const float* lnb  = (const float*)d_in[7];
  const float* lzg  = (const float*)d_in[8];
  const float* lzb  = (const float*)d_in[9];
  const float* fc1w = (const float*)d_in[10];
  const float* fc1b = (const float*)d_in[11];
  const float* fc2w = (const float*)d_in[12];
  const float* fc2b = (const float*)d_in[13];
  float* S = (float*)d_out;

  float* xcf  = (float*)d_ws;                 // 30720 f32
  float* ocum = xcf + 30720;                  // 10240 f32
  unsigned* bar = (unsigned*)(ocum + 10240);  // 512 u32
  float* Smir = (float*)(bar + 512);          // 40*30*1024 f32
  float* Omir = Smir + 1228800;               // 40*10*1024 f32
  float* vmir = Omir + 409600;                // 40*10*1024 f32
  _Float16* hmir = (_Float16*)(vmir + 409600);  // 40*10*4096 f16
  _Float16* Wvh  = hmir + 1638400;
  _Float16* Woh  = Wvh + 10485760;
  _Float16* fc1h = Woh + 10485760;
  _Float16* fc2h = fc1h + 4194304;

  hipLaunchKernelGGL(k_cvt, dim3(5120), dim3(256), 0, stream, Wv, Wvh, 1310720);
  hipLaunchKernelGGL(k_cvt, dim3(5120), dim3(256), 0, stream, Wo, Woh, 1310720);
  hipLaunchKernelGGL(k_cvt, dim3(2048), dim3(256), 0, stream, fc1w, fc1h, 524288);
  hipLaunchKernelGGL(k_cvt, dim3(2048), dim3(256), 0, stream, fc2w, fc2h, 524288);
  hipLaunchKernelGGL(k_xcf, dim3((NT * MDIM + 255) / 256), dim3(256), 0, stream, x, xcf);
  hipLaunchKernelGGL(k_s0, dim3(NT * MDIM / 4), dim3(256), 0, stream, xcf, W, S, Smir);
  hipMemsetAsync(ocum, 0, 10240 * sizeof(float), stream);
  hipMemsetAsync(Omir, 0, 409600 * sizeof(float), stream);
  hipMemsetAsync(bar, 0, 2048, stream);

  void* args[] = {(void*)&Wvh, (void*)&Woh, (void*)&fc1h, (void*)&fc1b,
                  (void*)&fc2h, (void*)&fc2b, (void*)&lng, (void*)&lnb,
                  (void*)&lzg, (void*)&lzb, (void*)&S,   (void*)&ocum,
                  (void*)&Smir, (void*)&Omir, (void*)&vmir, (void*)&hmir,
                  (void*)&bar};
  hipLaunchCooperativeKernel((void*)k_main, dim3(GBLK), dim3(GTHR), args, 0, stream);
}